// Round 2
// baseline (376.344 us; speedup 1.0000x reference)
//
#include <hip/hip_runtime.h>
#include <hip/hip_bf16.h>

typedef unsigned short u16;
typedef short bf16x8 __attribute__((ext_vector_type(8)));   // 8 bf16 = 4 VGPRs
typedef float f32x4 __attribute__((ext_vector_type(4)));

#define SS_PTS 2048

// workspace byte offsets (all 16B-aligned)
#define OFF_IDX   0ULL         // int  [65536*3]
#define OFF_W     786432ULL    // f32  [65536*3]
#define OFF_WT1B  1572864ULL   // bf16 [256][320]
#define OFF_WT2B  1736704ULL   // bf16 [128][256]
#define OFF_ST1   1802240ULL   // f32  [512]
#define OFF_ST2   1804288ULL   // f32  [256]
#define OFF_P1    1805312ULL   // f32  [1024][512]
#define OFF_P2    3902464ULL   // f32  [1024][256]
#define OFF_H1    4950016ULL   // bf16 tiled [8][65536][32]
#define OFF_H2    38504448ULL  // bf16 [65536][128]; ALSO G [16384][256] bf16
                               // (G consumed by gemm1 before gemm2 writes h2)

__device__ __forceinline__ u16 f2bf(float x) {
    union { __hip_bfloat16 h; u16 u; } cv;
    cv.h = __float2bfloat16(x);
    return cv.u;
}
__device__ __forceinline__ float bf2f(u16 u) {
    union { unsigned int i; float f; } cv;
    cv.i = ((unsigned int)u) << 16;
    return cv.f;
}
__device__ __forceinline__ float4 pack8(const float* v) {
    union { u16 u[8]; float4 f; } pk;
    #pragma unroll
    for (int j = 0; j < 8; ++j) pk.u[j] = f2bf(v[j]);
    return pk.f;
}

// ---------------------------------------------------------------- prep: W -> bf16
__global__ __launch_bounds__(256) void prep_kernel(
    const float* __restrict__ W1, const float* __restrict__ W2,
    u16* __restrict__ wt1b, u16* __restrict__ wt2b) {
    int i = blockIdx.x * 256 + threadIdx.x;
    if (i < 81920) wt1b[i] = f2bf(W1[i]);
    if (i < 32768) wt2b[i] = f2bf(W2[i]);
}

// ---------------------------------------------------------------- GEMM0
// G[16384][256] = points2[16384][256] @ W1b^T  (W1b = wt1b cols 64..319)
__global__ __launch_bounds__(256) void gemm0_kernel(
    const float* __restrict__ points2, const u16* __restrict__ wt1b,
    u16* __restrict__ G) {
    __shared__ __align__(16) u16 Bs[8192];   // 256 rows x 32 k, XOR-swizzled

    int t = threadIdx.x, bx = blockIdx.x;
    int R0 = bx * 64;
    int w = t >> 6, l = t & 63, l15 = l & 15, q = l >> 4;
    int wr = (w >> 1) * 32, wc = (w & 1) * 128;
    int bm = t >> 1, bh = t & 1;
    int sb0 = (bm >> 1) & 3, sb1 = ((bm + 128) >> 1) & 3;
    const u16* wsrc0 = wt1b + (size_t)bm * 320 + 64 + bh * 16;
    const u16* wsrc1 = wt1b + (size_t)(bm + 128) * 320 + 64 + bh * 16;

    float4 pb0 = ((const float4*)wsrc0)[0], pb1 = ((const float4*)wsrc0)[1];
    float4 pb2 = ((const float4*)wsrc1)[0], pb3 = ((const float4*)wsrc1)[1];

    f32x4 acc[2][8];
    #pragma unroll
    for (int i = 0; i < 2; ++i)
        #pragma unroll
        for (int j = 0; j < 8; ++j) acc[i][j] = (f32x4){0.f, 0.f, 0.f, 0.f};

    #pragma unroll
    for (int kb = 0; kb < 8; ++kb) {
        *(float4*)&Bs[bm * 32 + (((bh * 2 + 0) ^ sb0) << 3)] = pb0;
        *(float4*)&Bs[bm * 32 + (((bh * 2 + 1) ^ sb0) << 3)] = pb1;
        *(float4*)&Bs[(bm + 128) * 32 + (((bh * 2 + 0) ^ sb1) << 3)] = pb2;
        *(float4*)&Bs[(bm + 128) * 32 + (((bh * 2 + 1) ^ sb1) << 3)] = pb3;
        __syncthreads();
        if (kb < 7) {
            pb0 = ((const float4*)(wsrc0 + (kb + 1) * 32))[0];
            pb1 = ((const float4*)(wsrc0 + (kb + 1) * 32))[1];
            pb2 = ((const float4*)(wsrc1 + (kb + 1) * 32))[0];
            pb3 = ((const float4*)(wsrc1 + (kb + 1) * 32))[1];
        }
        union uf { float4 f; bf16x8 v; };
        uf af[2], bf8[8];
        #pragma unroll
        for (int fi = 0; fi < 2; ++fi) {
            int ml = wr + fi * 16 + l15;
            const float* s = points2 + (size_t)(R0 + ml) * 256 + kb * 32 + q * 8;
            float4 x0 = ((const float4*)s)[0], x1 = ((const float4*)s)[1];
            float va[8] = {x0.x, x0.y, x0.z, x0.w, x1.x, x1.y, x1.z, x1.w};
            af[fi].f = pack8(va);
        }
        #pragma unroll
        for (int fj = 0; fj < 8; ++fj) {
            int nl = wc + fj * 16 + l15;
            bf8[fj].f = *(const float4*)&Bs[nl * 32 + ((q ^ ((nl >> 1) & 3)) << 3)];
        }
        #pragma unroll
        for (int fi = 0; fi < 2; ++fi)
            #pragma unroll
            for (int fj = 0; fj < 8; ++fj)
                acc[fi][fj] = __builtin_amdgcn_mfma_f32_16x16x32_bf16(
                    bf8[fj].v, af[fi].v, acc[fi][fj], 0, 0, 0);
        __syncthreads();
    }

    #pragma unroll
    for (int fi = 0; fi < 2; ++fi) {
        int rg = R0 + wr + fi * 16 + l15;
        #pragma unroll
        for (int fj = 0; fj < 8; ++fj) {
            int cl = wc + fj * 16 + q * 4;
            union { u16 u[4]; float2 f; } pk;
            #pragma unroll
            for (int i = 0; i < 4; ++i) pk.u[i] = f2bf(acc[fi][fj][i]);
            *(float2*)&G[(size_t)rg * 256 + cl] = pk.f;
        }
    }
}

// ---------------------------------------------------------------- 3-NN + weights
// v8: 256 blocks x 256 queries. R=4 queries/thread (LDS reads amortized 4x),
// P=4 point-partitions, fully BRANCHLESS sorted-3 insert via min/med3 network
// (no exec-mask churn: wave-any insert probability was ~74%, so the branch
// bought nothing and cost scalar overhead + scheduling freedom).
__global__ __launch_bounds__(256) void knn_kernel(
    const float* __restrict__ xyz1, const float* __restrict__ xyz2,
    int* __restrict__ idxb, float* __restrict__ wb) {
    __shared__ float4 pts[2051];          // 4 regions of 513 (bank stagger)
    __shared__ float cd[64][4][4][3];     // [g][p][r][e]
    __shared__ int   ci[64][4][4][3];
    int t = threadIdx.x;
    int bx = blockIdx.x;
    int b = bx >> 5;                      // batch
    int q0 = (bx & 31) << 8;              // query base within batch (256/block)
    const float* x2b = xyz2 + (size_t)b * SS_PTS * 3;
    for (int j = t; j < SS_PTS; j += 256) {
        float x = x2b[j * 3 + 0], y = x2b[j * 3 + 1], z = x2b[j * 3 + 2];
        pts[(j >> 9) * 513 + (j & 511)] = make_float4(x, y, z, x * x + y * y + z * z);
    }
    int g = t >> 2, p = t & 3;
    size_t qb = (size_t)b * 8192 + q0 + g * 4;
    float m2x[4], m2y[4], m2z[4];
    #pragma unroll
    for (int r = 0; r < 4; ++r) {
        float qx = xyz1[(qb + r) * 3 + 0];
        float qy = xyz1[(qb + r) * 3 + 1];
        float qz = xyz1[(qb + r) * 3 + 2];
        m2x[r] = -2.0f * qx; m2y[r] = -2.0f * qy; m2z[r] = -2.0f * qz;
    }
    float d0[4], d1[4], d2[4];
    int j0[4], j1[4], j2[4];
    #pragma unroll
    for (int r = 0; r < 4; ++r) {
        d0[r] = 3.4e38f; d1[r] = 3.4e38f; d2[r] = 3.4e38f;
        j0[r] = 0; j1[r] = 0; j2[r] = 0;
    }
    __syncthreads();

    int base = p * 513, sbase = p * 512;
    #pragma unroll 4
    for (int s = 0; s < 512; ++s) {
        float4 pt = pts[base + s];
        int sj = sbase + s;
        #pragma unroll
        for (int r = 0; r < 4; ++r) {
            float sc = fmaf(m2x[r], pt.x, fmaf(m2y[r], pt.y, fmaf(m2z[r], pt.z, pt.w)));
            bool c0 = sc < d0[r], c1 = sc < d1[r], c2 = sc < d2[r];
            // sorted triple update: min + med3 + med3 (clamp idiom fuses)
            float nd0 = fminf(sc, d0[r]);
            float nd1 = fminf(fmaxf(sc, d0[r]), d1[r]);
            float nd2 = fminf(fmaxf(sc, d1[r]), d2[r]);
            int nj0 = c0 ? sj : j0[r];
            int nj1 = c1 ? (c0 ? j0[r] : sj) : j1[r];
            int nj2 = c2 ? (c1 ? j1[r] : sj) : j2[r];
            d0[r] = nd0; d1[r] = nd1; d2[r] = nd2;
            j0[r] = nj0; j1[r] = nj1; j2[r] = nj2;
        }
    }

    #pragma unroll
    for (int r = 0; r < 4; ++r) {
        cd[g][p][r][0] = d0[r]; cd[g][p][r][1] = d1[r]; cd[g][p][r][2] = d2[r];
        ci[g][p][r][0] = j0[r]; ci[g][p][r][1] = j1[r]; ci[g][p][r][2] = j2[r];
    }
    __syncthreads();

    // merge: thread t owns query q0+t; partials live at cd[t>>2][pp][t&3][e]
    int mg = t >> 2, mr = t & 3;
    float e0 = 3.4e38f, e1 = 3.4e38f, e2 = 3.4e38f;
    int k0 = 0, k1 = 0, k2 = 0;
    #pragma unroll
    for (int pp = 0; pp < 4; ++pp) {
        #pragma unroll
        for (int e = 0; e < 3; ++e) {
            float sc = cd[mg][pp][mr][e];
            int sj = ci[mg][pp][mr][e];
            bool c0 = sc < e0, c1 = sc < e1, c2 = sc < e2;
            float n0 = fminf(sc, e0);
            float n1 = fminf(fmaxf(sc, e0), e1);
            float n2 = fminf(fmaxf(sc, e1), e2);
            int m0 = c0 ? sj : k0;
            int m1 = c1 ? (c0 ? k0 : sj) : k1;
            int m2 = c2 ? (c1 ? k1 : sj) : k2;
            e0 = n0; e1 = n1; e2 = n2;
            k0 = m0; k1 = m1; k2 = m2;
        }
    }
    size_t gq = (size_t)b * 8192 + q0 + t;
    float qx = xyz1[gq * 3 + 0], qy = xyz1[gq * 3 + 1], qz = xyz1[gq * 3 + 2];
    float qq = qx * qx + qy * qy + qz * qz;
    float dd0 = fmaxf(e0 + qq, 1e-10f);
    float dd1 = fmaxf(e1 + qq, 1e-10f);
    float dd2 = fmaxf(e2 + qq, 1e-10f);
    float w0 = 1.0f / dd0, w1 = 1.0f / dd1, w2 = 1.0f / dd2;
    float inv = 1.0f / (w0 + w1 + w2);
    idxb[gq * 3 + 0] = k0;
    idxb[gq * 3 + 1] = k1;
    idxb[gq * 3 + 2] = k2;
    wb[gq * 3 + 0] = w0 * inv;
    wb[gq * 3 + 1] = w1 * inv;
    wb[gq * 3 + 2] = w2 * inv;
}

// ---------------------------------------------------------------- GEMM1 v7
// h1 = points1 @ W1a^T (K=64 MFMA) + Sum_k w_k * G[idx_k].
// v7: NO LDS atomics — stats via shfl-reduce over the 16 row-lanes into
// per-wave-pair LDS slices (each slot written by exactly one lane).
// idx/w read via uniform-address broadcast loads (no LDS staging).
__global__ __launch_bounds__(256, 3) void gemm1_kernel(
    const float* __restrict__ points1, const u16* __restrict__ G,
    const int* __restrict__ idxb, const float* __restrict__ wb,
    const u16* __restrict__ wt1b, u16* __restrict__ h1, float* __restrict__ part1) {
    __shared__ __align__(16) u16 Si[64 * 258];     // interp bf16, stride 258
    __shared__ __align__(16) u16 Bs[8192];         // W1a tile 256x32, swizzled
    __shared__ float bsum[2][256], bsq[2][256];    // per-wave-pair slices

    int t = threadIdx.x, bx = blockIdx.x;
    int batch = bx & 7;
    int R0 = batch * 8192 + (bx >> 3) * 64;
    const u16* Gb = G + (size_t)batch * SS_PTS * 256;

    int w = t >> 6, l = t & 63, l15 = l & 15, q = l >> 4;
    int wr = (w >> 1) * 32, wc = (w & 1) * 128;

    // ---- phase 1: gather-sum from G into Si; one wave per query row
    {
        #pragma unroll 4
        for (int e = 0; e < 16; ++e) {
            int qi = w * 16 + e;
            size_t gq = (size_t)(R0 + qi) * 3;
            int i0 = idxb[gq + 0], i1 = idxb[gq + 1], i2 = idxb[gq + 2];
            float w0 = wb[gq + 0], w1 = wb[gq + 1], w2 = wb[gq + 2];
            union { float2 f; u16 u[4]; } g0, g1, g2;
            g0.f = *(const float2*)(Gb + (size_t)i0 * 256 + l * 4);
            g1.f = *(const float2*)(Gb + (size_t)i1 * 256 + l * 4);
            g2.f = *(const float2*)(Gb + (size_t)i2 * 256 + l * 4);
            union { u16 u[4]; float2 f; } pk;
            #pragma unroll
            for (int i = 0; i < 4; ++i) {
                float v = fmaf(w0, bf2f(g0.u[i]),
                          fmaf(w1, bf2f(g1.u[i]), w2 * bf2f(g2.u[i])));
                pk.u[i] = f2bf(v);
            }
            *(float2*)&Si[qi * 258 + l * 4] = pk.f;
        }
    }

    // ---- B staging regs (W1a rows, k 0..63)
    int bm = t >> 1, bh = t & 1;
    int sb0 = (bm >> 1) & 3, sb1 = ((bm + 128) >> 1) & 3;
    const u16* wsrc0 = wt1b + (size_t)bm * 320 + bh * 16;
    const u16* wsrc1 = wt1b + (size_t)(bm + 128) * 320 + bh * 16;
    float4 pb0 = ((const float4*)wsrc0)[0], pb1 = ((const float4*)wsrc0)[1];
    float4 pb2 = ((const float4*)wsrc1)[0], pb3 = ((const float4*)wsrc1)[1];

    f32x4 acc[2][8];
    #pragma unroll
    for (int i = 0; i < 2; ++i)
        #pragma unroll
        for (int j = 0; j < 8; ++j) acc[i][j] = (f32x4){0.f, 0.f, 0.f, 0.f};

    // ---- phase 2: K-loop (2 x K=32) on points1 @ W1a^T
    #pragma unroll
    for (int kb = 0; kb < 2; ++kb) {
        *(float4*)&Bs[bm * 32 + (((bh * 2 + 0) ^ sb0) << 3)] = pb0;
        *(float4*)&Bs[bm * 32 + (((bh * 2 + 1) ^ sb0) << 3)] = pb1;
        *(float4*)&Bs[(bm + 128) * 32 + (((bh * 2 + 0) ^ sb1) << 3)] = pb2;
        *(float4*)&Bs[(bm + 128) * 32 + (((bh * 2 + 1) ^ sb1) << 3)] = pb3;
        __syncthreads();
        if (kb == 0) {
            pb0 = ((const float4*)(wsrc0 + 32))[0];
            pb1 = ((const float4*)(wsrc0 + 32))[1];
            pb2 = ((const float4*)(wsrc1 + 32))[0];
            pb3 = ((const float4*)(wsrc1 + 32))[1];
        }
        union uf { float4 f; bf16x8 v; };
        uf af[2], bf8[8];
        #pragma unroll
        for (int fi = 0; fi < 2; ++fi) {
            int ml = wr + fi * 16 + l15;
            const float* s = points1 + (size_t)(R0 + ml) * 64 + kb * 32 + q * 8;
            float4 x0 = ((const float4*)s)[0], x1 = ((const float4*)s)[1];
            float va[8] = {x0.x, x0.y, x0.z, x0.w, x1.x, x1.y, x1.z, x1.w};
            af[fi].f = pack8(va);
        }
        #pragma unroll
        for (int fj = 0; fj < 8; ++fj) {
            int nl = wc + fj * 16 + l15;
            bf8[fj].f = *(const float4*)&Bs[nl * 32 + ((q ^ ((nl >> 1) & 3)) << 3)];
        }
        #pragma unroll
        for (int fi = 0; fi < 2; ++fi)
            #pragma unroll
            for (int fj = 0; fj < 8; ++fj)
                acc[fi][fj] = __builtin_amdgcn_mfma_f32_16x16x32_bf16(
                    bf8[fj].v, af[fi].v, acc[fi][fj], 0, 0, 0);
        __syncthreads();
    }

    // ---- epilogue: add interp (Si), store h1 K-tiled, stats via shfl (no atomics)
    #pragma unroll
    for (int fj = 0; fj < 8; ++fj) {
        int c0 = wc + fj * 16 + q * 4;
        float s[4], sq[4];
        #pragma unroll
        for (int i = 0; i < 4; ++i) { s[i] = 0.0f; sq[i] = 0.0f; }
        #pragma unroll
        for (int fi = 0; fi < 2; ++fi) {
            int rl = wr + fi * 16 + l15;
            int rg = R0 + rl;
            union { float2 f; u16 u[4]; } si;
            si.f = *(const float2*)&Si[rl * 258 + c0];
            union { u16 u[4]; float2 f; } pk;
            #pragma unroll
            for (int i = 0; i < 4; ++i) {
                float v = acc[fi][fj][i] + bf2f(si.u[i]);
                pk.u[i] = f2bf(v);
                s[i] += v; sq[i] += v * v;
            }
            *(float2*)&h1[((size_t)(c0 >> 5) * 65536 + rg) * 32 + (c0 & 31)] = pk.f;
        }
        #pragma unroll
        for (int i = 0; i < 4; ++i) {
            #pragma unroll
            for (int d = 1; d < 16; d <<= 1) {
                s[i]  += __shfl_xor(s[i], d, 16);
                sq[i] += __shfl_xor(sq[i], d, 16);
            }
        }
        if (l15 == 0) {
            int half = w >> 1;
            #pragma unroll
            for (int i = 0; i < 4; ++i) {
                bsum[half][c0 + i] = s[i];
                bsq[half][c0 + i]  = sq[i];
            }
        }
    }
    __syncthreads();
    part1[(size_t)bx * 512 + t * 2 + 0] = bsum[0][t] + bsum[1][t];
    part1[(size_t)bx * 512 + t * 2 + 1] = bsq[0][t] + bsq[1][t];
}

// ---------------------------------------------------------------- stats reduce
__global__ __launch_bounds__(256) void reduce_kernel(
    const float* __restrict__ part, int nblk, int C, float invM,
    const float* __restrict__ gam, const float* __restrict__ bet,
    float* __restrict__ st) {
    __shared__ float red[256];
    int t = threadIdx.x;
    int slot = t & 31, ig = t >> 5;
    int cb = blockIdx.x * 16;
    float p = 0.0f;
    for (int i = ig; i < nblk; i += 8)
        p += part[(size_t)i * (2 * C) + cb * 2 + slot];
    red[t] = p;
    __syncthreads();
    if (t < 32) {
        float tot = red[t];
        #pragma unroll
        for (int k = 1; k < 8; ++k) tot += red[k * 32 + t];
        red[t] = tot;
    }
    __syncthreads();
    if (t < 16) {
        int c = cb + t;
        float sum = red[2 * t], sq = red[2 * t + 1];
        float mean = sum * invM;
        float var  = sq * invM - mean * mean;
        float rs   = rsqrtf(var + 1e-5f);
        float scv  = gam[c] * rs;
        st[c]     = scv;
        st[C + c] = bet[c] - mean * scv;
    }
}

// ---------------------------------------------------------------- GEMM2 v7
// 64x128 tile, grid 1024, LDS dbuf + reg prefetch. Stats: shfl + per-wave
// LDS slices (no atomics).
__global__ __launch_bounds__(256, 4) void gemm2_kernel(
    const u16* __restrict__ h1, const u16* __restrict__ wt2b,
    const float* __restrict__ st1,
    u16* __restrict__ h2, float* __restrict__ part2) {
    __shared__ __align__(16) u16 As[2][64 * 32];
    __shared__ __align__(16) u16 Bs[2][128 * 32];
    __shared__ float sc1[256], sh1[256];
    __shared__ float bsum2[4][128], bsq2[4][128];

    int t = threadIdx.x;
    int bx = blockIdx.x;
    int R0 = bx * 64;
    sc1[t] = st1[t];
    sh1[t] = st1[256 + t];

    int w = t >> 6, l = t & 63, l15 = l & 15, q = l >> 4;
    int wr = w * 16;
    int arow = t >> 2, ac8 = (t & 3) << 3, sa = (arow >> 1) & 3;
    int bm = t >> 1, bh = t & 1, sb = (bm >> 1) & 3;

    union lda_t { float4 f; u16 u[8]; };
    lda_t pa; float4 pb0, pb1;
    const u16* bsrc = wt2b + (size_t)bm * 256 + bh * 16;

    pa.f = *(const float4*)(h1 + ((size_t)0 * 65536 + R0 + arow) * 32 + ac8);
    pb0 = ((const float4*)bsrc)[0];
    pb1 = ((const float4*)bsrc)[1];

    f32x4 acc[8];
    #pragma unroll
    for (int j = 0; j < 8; ++j) acc[j] = (f32x4){0.f, 0.f, 0.f, 0.f};

    __syncthreads();   // sc1/sh1 visible

    {
        float o[8];
        #pragma unroll
        for (int j = 0; j < 8; ++j)
            o[j] = fmaxf(fmaf(bf2f(pa.u[j]), sc1[ac8 + j], sh1[ac8 + j]), 0.0f);
        *(float4*)&As[0][arow * 32 + (((ac8 >> 3) ^ sa) << 3)] = pack8(o);
        *(float4*)&Bs[0][bm * 32 + (((bh * 2 + 0) ^ sb) << 3)] = pb0;
        *(float4*)&Bs[0][bm * 32 + (((bh * 2 + 1) ^ sb) << 3)] = pb1;
    }
    __syncthreads();

    #pragma unroll
    for (int kb = 0; kb < 8; ++kb) {
        if (kb < 7) {
            pa.f = *(const float4*)(h1 + ((size_t)(kb + 1) * 65536 + R0 + arow) * 32 + ac8);
            pb0 = ((const float4*)(bsrc + (kb + 1) * 32))[0];
            pb1 = ((const float4*)(bsrc + (kb + 1) * 32))[1];
        }
        int buf = kb & 1;
        union uf { float4 f; bf16x8 v; };
        uf af, bf8[8];
        {
            int ml = wr + l15;
            af.f = *(const float4*)&As[buf][ml * 32 + ((q ^ ((ml >> 1) & 3)) << 3)];
        }
        #pragma unroll
        for (int fj = 0; fj < 8; ++fj) {
            int nl = fj * 16 + l15;
            bf8[fj].f = *(const float4*)&Bs[buf][nl * 32 + ((q ^ ((nl >> 1) & 3)) << 3)];
        }
        #pragma unroll
        for (int fj = 0; fj < 8; ++fj)
            acc[fj] = __builtin_amdgcn_mfma_f32_16x16x32_bf16(
                bf8[fj].v, af.v, acc[fj], 0, 0, 0);
        if (kb < 7) {
            int ch0 = (kb + 1) * 32 + ac8;
            float o[8];
            #pragma unroll
            for (int j = 0; j < 8; ++j)
                o[j] = fmaxf(fmaf(bf2f(pa.u[j]), sc1[ch0 + j], sh1[ch0 + j]), 0.0f);
            *(float4*)&As[buf ^ 1][arow * 32 + (((ac8 >> 3) ^ sa) << 3)] = pack8(o);
            *(float4*)&Bs[buf ^ 1][bm * 32 + (((bh * 2 + 0) ^ sb) << 3)] = pb0;
            *(float4*)&Bs[buf ^ 1][bm * 32 + (((bh * 2 + 1) ^ sb) << 3)] = pb1;
        }
        __syncthreads();
    }

    // ---- epilogue: h2 store + stats via shfl into per-wave slices (no atomics)
    int rg = R0 + wr + l15;
    #pragma unroll
    for (int fj = 0; fj < 8; ++fj) {
        int cl = fj * 16 + q * 4;
        union { u16 u[4]; float2 f; } pk;
        float s[4], sq[4];
        #pragma unroll
        for (int i = 0; i < 4; ++i) {
            float v = acc[fj][i];
            pk.u[i] = f2bf(v);
            s[i] = v; sq[i] = v * v;
        }
        *(float2*)&h2[(size_t)rg * 128 + cl] = pk.f;
        #pragma unroll
        for (int i = 0; i < 4; ++i) {
            #pragma unroll
            for (int d = 1; d < 16; d <<= 1) {
                s[i]  += __shfl_xor(s[i], d, 16);
                sq[i] += __shfl_xor(sq[i], d, 16);
            }
        }
        if (l15 == 0) {
            #pragma unroll
            for (int i = 0; i < 4; ++i) {
                bsum2[w][cl + i] = s[i];
                bsq2[w][cl + i]  = sq[i];
            }
        }
    }
    __syncthreads();
    if (t < 128) {
        part2[(size_t)bx * 256 + t * 2 + 0] =
            bsum2[0][t] + bsum2[1][t] + bsum2[2][t] + bsum2[3][t];
        part2[(size_t)bx * 256 + t * 2 + 1] =
            bsq2[0][t] + bsq2[1][t] + bsq2[2][t] + bsq2[3][t];
    }
}

// ---------------------------------------------------------------- final BN2 + relu
__global__ __launch_bounds__(256) void final_kernel(
    const u16* __restrict__ h2, const float* __restrict__ st2,
    float* __restrict__ out) {
    __shared__ float lst[256];
    int t = threadIdx.x;
    lst[t] = st2[t];
    __syncthreads();
    size_t e0 = ((size_t)blockIdx.x * 256 + t) * 8;
    int c0 = (int)(e0 & 127);
    union { float4 f; u16 u[8]; } ld;
    ld.f = *(const float4*)(h2 + e0);
    float o[8];
    #pragma unroll
    for (int j = 0; j < 8; ++j) {
        int c = c0 + j;
        float v = fmaf(bf2f(ld.u[j]), lst[c], lst[128 + c]);
        o[j] = fmaxf(v, 0.0f);
    }
    float4* op = (float4*)(out + e0);
    float4 r0; r0.x = o[0]; r0.y = o[1]; r0.z = o[2]; r0.w = o[3];
    float4 r1; r1.x = o[4]; r1.y = o[5]; r1.z = o[6]; r1.w = o[7];
    op[0] = r0;
    op[1] = r1;
}

// ----------------------------------------------------------------
extern "C" void kernel_launch(void* const* d_in, const int* in_sizes, int n_in,
                              void* d_out, int out_size, void* d_ws, size_t ws_size,
                              hipStream_t stream) {
    (void)in_sizes; (void)n_in; (void)out_size; (void)ws_size;
    const float* xyz1    = (const float*)d_in[0];
    const float* xyz2    = (const float*)d_in[1];
    const float* points1 = (const float*)d_in[2];
    const float* points2 = (const float*)d_in[3];
    const float* W1      = (const float*)d_in[4];
    const float* g1      = (const float*)d_in[5];
    const float* b1      = (const float*)d_in[6];
    const float* W2      = (const float*)d_in[7];
    const float* g2      = (const float*)d_in[8];
    const float* b2      = (const float*)d_in[9];

    char* ws = (char*)d_ws;
    int*   idxb = (int*)(ws + OFF_IDX);
    float* wb   = (float*)(ws + OFF_W);
    u16*   wt1b = (u16*)(ws + OFF_WT1B);
    u16*   wt2b = (u16*)(ws + OFF_WT2B);
    float* st1  = (float*)(ws + OFF_ST1);
    float* st2  = (float*)(ws + OFF_ST2);
    float* p1   = (float*)(ws + OFF_P1);
    float* p2   = (float*)(ws + OFF_P2);
    u16*   h1   = (u16*)(ws + OFF_H1);
    u16*   h2   = (u16*)(ws + OFF_H2);
    u16*   G    = (u16*)(ws + OFF_H2);   // reuse: consumed before h2 is written
    float* outp = (float*)d_out;

    prep_kernel<<<320, 256, 0, stream>>>(W1, W2, wt1b, wt2b);
    gemm0_kernel<<<256, 256, 0, stream>>>(points2, wt1b, G);
    knn_kernel<<<256, 256, 0, stream>>>(xyz1, xyz2, idxb, wb);
    gemm1_kernel<<<1024, 256, 0, stream>>>(points1, G, idxb, wb, wt1b, h1, p1);
    reduce_kernel<<<16, 256, 0, stream>>>(p1, 1024, 256, 1.0f / 65536.0f, g1, b1, st1);
    gemm2_kernel<<<1024, 256, 0, stream>>>(h1, wt2b, st1, h2, p2);
    reduce_kernel<<<8, 256, 0, stream>>>(p2, 1024, 128, 1.0f / 65536.0f, g2, b2, st2);
    final_kernel<<<4096, 256, 0, stream>>>(h2, st2, outp);
}

// Round 3
// 313.378 us; speedup vs baseline: 1.2009x; 1.2009x over previous
//
#include <hip/hip_runtime.h>
#include <hip/hip_bf16.h>

typedef unsigned short u16;
typedef short bf16x8 __attribute__((ext_vector_type(8)));   // 8 bf16 = 4 VGPRs
typedef float f32x4 __attribute__((ext_vector_type(4)));

#define SS_PTS 2048

// workspace byte offsets (all 16B-aligned)
#define OFF_IDX   0ULL         // int  [65536*3]
#define OFF_W     786432ULL    // f32  [65536*3]
#define OFF_WT1B  1572864ULL   // bf16 [256][320]
#define OFF_WT2B  1736704ULL   // bf16 [128][256]
#define OFF_ST1   1802240ULL   // f32  [512]
#define OFF_ST2   1804288ULL   // f32  [256]
#define OFF_P1    1805312ULL   // f32  [1024][512]
#define OFF_P2    3902464ULL   // f32  [1024][256]
#define OFF_H1    4950016ULL   // bf16 tiled [8][65536][32]
#define OFF_H2    38504448ULL  // bf16 [65536][128]; ALSO G [16384][256] bf16
                               // (G consumed by gemm1 before gemm2 writes h2)

__device__ __forceinline__ u16 f2bf(float x) {
    union { __hip_bfloat16 h; u16 u; } cv;
    cv.h = __float2bfloat16(x);
    return cv.u;
}
__device__ __forceinline__ float bf2f(u16 u) {
    union { unsigned int i; float f; } cv;
    cv.i = ((unsigned int)u) << 16;
    return cv.f;
}
__device__ __forceinline__ float4 pack8(const float* v) {
    union { u16 u[8]; float4 f; } pk;
    #pragma unroll
    for (int j = 0; j < 8; ++j) pk.u[j] = f2bf(v[j]);
    return pk.f;
}

// ---------------------------------------------------------------- prep: W -> bf16
__global__ __launch_bounds__(256) void prep_kernel(
    const float* __restrict__ W1, const float* __restrict__ W2,
    u16* __restrict__ wt1b, u16* __restrict__ wt2b) {
    int i = blockIdx.x * 256 + threadIdx.x;
    if (i < 81920) wt1b[i] = f2bf(W1[i]);
    if (i < 32768) wt2b[i] = f2bf(W2[i]);
}

// ---------------------------------------------------------------- GEMM0
// G[16384][256] = points2[16384][256] @ W1b^T  (W1b = wt1b cols 64..319)
__global__ __launch_bounds__(256) void gemm0_kernel(
    const float* __restrict__ points2, const u16* __restrict__ wt1b,
    u16* __restrict__ G) {
    __shared__ __align__(16) u16 Bs[8192];   // 256 rows x 32 k, XOR-swizzled

    int t = threadIdx.x, bx = blockIdx.x;
    int R0 = bx * 64;
    int w = t >> 6, l = t & 63, l15 = l & 15, q = l >> 4;
    int wr = (w >> 1) * 32, wc = (w & 1) * 128;
    int bm = t >> 1, bh = t & 1;
    int sb0 = (bm >> 1) & 3, sb1 = ((bm + 128) >> 1) & 3;
    const u16* wsrc0 = wt1b + (size_t)bm * 320 + 64 + bh * 16;
    const u16* wsrc1 = wt1b + (size_t)(bm + 128) * 320 + 64 + bh * 16;

    float4 pb0 = ((const float4*)wsrc0)[0], pb1 = ((const float4*)wsrc0)[1];
    float4 pb2 = ((const float4*)wsrc1)[0], pb3 = ((const float4*)wsrc1)[1];

    f32x4 acc[2][8];
    #pragma unroll
    for (int i = 0; i < 2; ++i)
        #pragma unroll
        for (int j = 0; j < 8; ++j) acc[i][j] = (f32x4){0.f, 0.f, 0.f, 0.f};

    #pragma unroll
    for (int kb = 0; kb < 8; ++kb) {
        *(float4*)&Bs[bm * 32 + (((bh * 2 + 0) ^ sb0) << 3)] = pb0;
        *(float4*)&Bs[bm * 32 + (((bh * 2 + 1) ^ sb0) << 3)] = pb1;
        *(float4*)&Bs[(bm + 128) * 32 + (((bh * 2 + 0) ^ sb1) << 3)] = pb2;
        *(float4*)&Bs[(bm + 128) * 32 + (((bh * 2 + 1) ^ sb1) << 3)] = pb3;
        __syncthreads();
        if (kb < 7) {
            pb0 = ((const float4*)(wsrc0 + (kb + 1) * 32))[0];
            pb1 = ((const float4*)(wsrc0 + (kb + 1) * 32))[1];
            pb2 = ((const float4*)(wsrc1 + (kb + 1) * 32))[0];
            pb3 = ((const float4*)(wsrc1 + (kb + 1) * 32))[1];
        }
        union uf { float4 f; bf16x8 v; };
        uf af[2], bf8[8];
        #pragma unroll
        for (int fi = 0; fi < 2; ++fi) {
            int ml = wr + fi * 16 + l15;
            const float* s = points2 + (size_t)(R0 + ml) * 256 + kb * 32 + q * 8;
            float4 x0 = ((const float4*)s)[0], x1 = ((const float4*)s)[1];
            float va[8] = {x0.x, x0.y, x0.z, x0.w, x1.x, x1.y, x1.z, x1.w};
            af[fi].f = pack8(va);
        }
        #pragma unroll
        for (int fj = 0; fj < 8; ++fj) {
            int nl = wc + fj * 16 + l15;
            bf8[fj].f = *(const float4*)&Bs[nl * 32 + ((q ^ ((nl >> 1) & 3)) << 3)];
        }
        #pragma unroll
        for (int fi = 0; fi < 2; ++fi)
            #pragma unroll
            for (int fj = 0; fj < 8; ++fj)
                acc[fi][fj] = __builtin_amdgcn_mfma_f32_16x16x32_bf16(
                    bf8[fj].v, af[fi].v, acc[fi][fj], 0, 0, 0);
        __syncthreads();
    }

    #pragma unroll
    for (int fi = 0; fi < 2; ++fi) {
        int rg = R0 + wr + fi * 16 + l15;
        #pragma unroll
        for (int fj = 0; fj < 8; ++fj) {
            int cl = wc + fj * 16 + q * 4;
            union { u16 u[4]; float2 f; } pk;
            #pragma unroll
            for (int i = 0; i < 4; ++i) pk.u[i] = f2bf(acc[fi][fj][i]);
            *(float2*)&G[(size_t)rg * 256 + cl] = pk.f;
        }
    }
}

// ---------------------------------------------------------------- 3-NN + weights
// v9: packed-key top-3. sc = |p-q|^2 + 4 in [4,36) -> (bits(sc)-bits(4.0))
// is a 25-bit monotone injective int; pack 7-bit in-partition index in the
// low bits -> sorted-3 insert is min_u32 + 2x med3_u32, ZERO cmp/cndmask.
// Exact f32 ordering for all d^2 < 32 (top-3 is << 8 for every query);
// >=32 saturates (never a true top-3). Low-clamp guards d^2~0 rounding.
// 2048 blocks x 32 queries (R=2/thread, P=16 partitions of 128) -> 4 blk/CU.
// Winner distances recomputed exactly from LDS for the weights.
__global__ __launch_bounds__(256) void knn_kernel(
    const float* __restrict__ xyz1, const float* __restrict__ xyz2,
    int* __restrict__ idxb, float* __restrict__ wb) {
    __shared__ float4 pts[2064];              // 16 regions of 129 (bank stagger)
    __shared__ unsigned int ck[16][16][2][3]; // [g][p][r][e] packed keys
    int t = threadIdx.x;
    int bx = blockIdx.x;
    int b = bx >> 8;                          // batch (256 blocks per batch)
    int q0 = (bx & 255) << 5;                 // 32 queries per block
    const float* x2b = xyz2 + (size_t)b * SS_PTS * 3;
    for (int j = t; j < SS_PTS; j += 256) {
        float x = x2b[j * 3 + 0], y = x2b[j * 3 + 1], z = x2b[j * 3 + 2];
        float pw4 = fmaf(x, x, fmaf(y, y, fmaf(z, z, 4.0f)));
        pts[(j >> 7) * 129 + (j & 127)] = make_float4(x, y, z, pw4);
    }
    int g = t >> 4, p = t & 15;
    size_t qb = (size_t)b * 8192 + q0 + g * 2;
    float m2x[2], m2y[2], m2z[2], qq[2];
    #pragma unroll
    for (int r = 0; r < 2; ++r) {
        float qx = xyz1[(qb + r) * 3 + 0];
        float qy = xyz1[(qb + r) * 3 + 1];
        float qz = xyz1[(qb + r) * 3 + 2];
        m2x[r] = -2.0f * qx; m2y[r] = -2.0f * qy; m2z[r] = -2.0f * qz;
        qq[r] = fmaf(qx, qx, fmaf(qy, qy, qz * qz));
    }
    unsigned int k0[2], k1[2], k2[2];
    #pragma unroll
    for (int r = 0; r < 2; ++r) { k0[r] = 0xFFFFFFFFu; k1[r] = 0xFFFFFFFFu; k2[r] = 0xFFFFFFFFu; }
    __syncthreads();

    const int BASE_BITS = 0x40800000;         // bits(4.0f)
    const int KD_CAP    = 0x01900000 - 1;     // bits(36.0f)-bits(4.0f)-1, 25-bit
    int base = p * 129;                       // float4 index of partition start
    #pragma unroll 4
    for (int s = 0; s < 128; ++s) {
        float4 pt = pts[base + s];
        #pragma unroll
        for (int r = 0; r < 2; ++r) {
            float sc = fmaf(m2x[r], pt.x, fmaf(m2y[r], pt.y, fmaf(m2z[r], pt.z, pt.w))) + qq[r];
            int su = (int)__float_as_uint(sc) - BASE_BITS;
            int kd = su < 0 ? 0 : (su > KD_CAP ? KD_CAP : su);   // med3_i32
            unsigned int key = ((unsigned int)kd << 7) | (unsigned int)s;
            unsigned int o0 = k0[r], o1 = k1[r];
            unsigned int mx0 = key > o0 ? key : o0;
            unsigned int mx1 = key > o1 ? key : o1;
            k0[r] = key < o0 ? key : o0;                          // min_u32
            k1[r] = mx0 < k1[r] ? mx0 : k1[r];                    // med3_u32
            k2[r] = mx1 < k2[r] ? mx1 : k2[r];                    // med3_u32
        }
    }

    #pragma unroll
    for (int r = 0; r < 2; ++r) {
        ck[g][p][r][0] = k0[r]; ck[g][p][r][1] = k1[r]; ck[g][p][r][2] = k2[r];
    }
    __syncthreads();

    // merge: thread t (t<32) owns query q0+t; 16 partitions x 3 candidates.
    if (t < 32) {
        int mg = t >> 1, mr = t & 1;
        // track (key, global index) pairs; cost here is negligible (32 thr)
        unsigned int e0 = 0xFFFFFFFFu, e1 = 0xFFFFFFFFu, e2 = 0xFFFFFFFFu;
        int J0 = 0, J1 = 0, J2 = 0;
        #pragma unroll
        for (int pp = 0; pp < 16; ++pp) {
            #pragma unroll
            for (int e = 0; e < 3; ++e) {
                unsigned int key = ck[mg][pp][mr][e];
                int sj = pp * 128 + (int)(key & 127u);
                bool c0 = key < e0, c1 = key < e1, c2 = key < e2;
                unsigned int o0 = e0, o1 = e1;
                unsigned int mx0 = key > o0 ? key : o0;
                unsigned int mx1 = key > o1 ? key : o1;
                e0 = key < o0 ? key : o0;
                e1 = mx0 < e1 ? mx0 : e1;
                e2 = mx1 < e2 ? mx1 : e2;
                int nJ0 = c0 ? sj : J0;
                int nJ1 = c1 ? (c0 ? J0 : sj) : J1;
                int nJ2 = c2 ? (c1 ? J1 : sj) : J2;
                J0 = nJ0; J1 = nJ1; J2 = nJ2;
            }
        }
        size_t gq = (size_t)b * 8192 + q0 + t;
        float qx = xyz1[gq * 3 + 0], qy = xyz1[gq * 3 + 1], qz = xyz1[gq * 3 + 2];
        // exact distance recompute for the 3 winners
        float4 p0 = pts[(J0 >> 7) * 129 + (J0 & 127)];
        float4 p1 = pts[(J1 >> 7) * 129 + (J1 & 127)];
        float4 p2 = pts[(J2 >> 7) * 129 + (J2 & 127)];
        float dx0 = p0.x - qx, dy0 = p0.y - qy, dz0 = p0.z - qz;
        float dx1 = p1.x - qx, dy1 = p1.y - qy, dz1 = p1.z - qz;
        float dx2 = p2.x - qx, dy2 = p2.y - qy, dz2 = p2.z - qz;
        float dd0 = fmaxf(fmaf(dx0, dx0, fmaf(dy0, dy0, dz0 * dz0)), 1e-10f);
        float dd1 = fmaxf(fmaf(dx1, dx1, fmaf(dy1, dy1, dz1 * dz1)), 1e-10f);
        float dd2 = fmaxf(fmaf(dx2, dx2, fmaf(dy2, dy2, dz2 * dz2)), 1e-10f);
        float w0 = 1.0f / dd0, w1 = 1.0f / dd1, w2 = 1.0f / dd2;
        float inv = 1.0f / (w0 + w1 + w2);
        idxb[gq * 3 + 0] = J0;
        idxb[gq * 3 + 1] = J1;
        idxb[gq * 3 + 2] = J2;
        wb[gq * 3 + 0] = w0 * inv;
        wb[gq * 3 + 1] = w1 * inv;
        wb[gq * 3 + 2] = w2 * inv;
    }
}

// ---------------------------------------------------------------- GEMM1 v7
// h1 = points1 @ W1a^T (K=64 MFMA) + Sum_k w_k * G[idx_k].
// v7: NO LDS atomics — stats via shfl-reduce over the 16 row-lanes into
// per-wave-pair LDS slices (each slot written by exactly one lane).
// idx/w read via uniform-address broadcast loads (no LDS staging).
__global__ __launch_bounds__(256, 3) void gemm1_kernel(
    const float* __restrict__ points1, const u16* __restrict__ G,
    const int* __restrict__ idxb, const float* __restrict__ wb,
    const u16* __restrict__ wt1b, u16* __restrict__ h1, float* __restrict__ part1) {
    __shared__ __align__(16) u16 Si[64 * 258];     // interp bf16, stride 258
    __shared__ __align__(16) u16 Bs[8192];         // W1a tile 256x32, swizzled
    __shared__ float bsum[2][256], bsq[2][256];    // per-wave-pair slices

    int t = threadIdx.x, bx = blockIdx.x;
    int batch = bx & 7;
    int R0 = batch * 8192 + (bx >> 3) * 64;
    const u16* Gb = G + (size_t)batch * SS_PTS * 256;

    int w = t >> 6, l = t & 63, l15 = l & 15, q = l >> 4;
    int wr = (w >> 1) * 32, wc = (w & 1) * 128;

    // ---- phase 1: gather-sum from G into Si; one wave per query row
    {
        #pragma unroll 4
        for (int e = 0; e < 16; ++e) {
            int qi = w * 16 + e;
            size_t gq = (size_t)(R0 + qi) * 3;
            int i0 = idxb[gq + 0], i1 = idxb[gq + 1], i2 = idxb[gq + 2];
            float w0 = wb[gq + 0], w1 = wb[gq + 1], w2 = wb[gq + 2];
            union { float2 f; u16 u[4]; } g0, g1, g2;
            g0.f = *(const float2*)(Gb + (size_t)i0 * 256 + l * 4);
            g1.f = *(const float2*)(Gb + (size_t)i1 * 256 + l * 4);
            g2.f = *(const float2*)(Gb + (size_t)i2 * 256 + l * 4);
            union { u16 u[4]; float2 f; } pk;
            #pragma unroll
            for (int i = 0; i < 4; ++i) {
                float v = fmaf(w0, bf2f(g0.u[i]),
                          fmaf(w1, bf2f(g1.u[i]), w2 * bf2f(g2.u[i])));
                pk.u[i] = f2bf(v);
            }
            *(float2*)&Si[qi * 258 + l * 4] = pk.f;
        }
    }

    // ---- B staging regs (W1a rows, k 0..63)
    int bm = t >> 1, bh = t & 1;
    int sb0 = (bm >> 1) & 3, sb1 = ((bm + 128) >> 1) & 3;
    const u16* wsrc0 = wt1b + (size_t)bm * 320 + bh * 16;
    const u16* wsrc1 = wt1b + (size_t)(bm + 128) * 320 + bh * 16;
    float4 pb0 = ((const float4*)wsrc0)[0], pb1 = ((const float4*)wsrc0)[1];
    float4 pb2 = ((const float4*)wsrc1)[0], pb3 = ((const float4*)wsrc1)[1];

    f32x4 acc[2][8];
    #pragma unroll
    for (int i = 0; i < 2; ++i)
        #pragma unroll
        for (int j = 0; j < 8; ++j) acc[i][j] = (f32x4){0.f, 0.f, 0.f, 0.f};

    // ---- phase 2: K-loop (2 x K=32) on points1 @ W1a^T
    #pragma unroll
    for (int kb = 0; kb < 2; ++kb) {
        *(float4*)&Bs[bm * 32 + (((bh * 2 + 0) ^ sb0) << 3)] = pb0;
        *(float4*)&Bs[bm * 32 + (((bh * 2 + 1) ^ sb0) << 3)] = pb1;
        *(float4*)&Bs[(bm + 128) * 32 + (((bh * 2 + 0) ^ sb1) << 3)] = pb2;
        *(float4*)&Bs[(bm + 128) * 32 + (((bh * 2 + 1) ^ sb1) << 3)] = pb3;
        __syncthreads();
        if (kb == 0) {
            pb0 = ((const float4*)(wsrc0 + 32))[0];
            pb1 = ((const float4*)(wsrc0 + 32))[1];
            pb2 = ((const float4*)(wsrc1 + 32))[0];
            pb3 = ((const float4*)(wsrc1 + 32))[1];
        }
        union uf { float4 f; bf16x8 v; };
        uf af[2], bf8[8];
        #pragma unroll
        for (int fi = 0; fi < 2; ++fi) {
            int ml = wr + fi * 16 + l15;
            const float* s = points1 + (size_t)(R0 + ml) * 64 + kb * 32 + q * 8;
            float4 x0 = ((const float4*)s)[0], x1 = ((const float4*)s)[1];
            float va[8] = {x0.x, x0.y, x0.z, x0.w, x1.x, x1.y, x1.z, x1.w};
            af[fi].f = pack8(va);
        }
        #pragma unroll
        for (int fj = 0; fj < 8; ++fj) {
            int nl = wc + fj * 16 + l15;
            bf8[fj].f = *(const float4*)&Bs[nl * 32 + ((q ^ ((nl >> 1) & 3)) << 3)];
        }
        #pragma unroll
        for (int fi = 0; fi < 2; ++fi)
            #pragma unroll
            for (int fj = 0; fj < 8; ++fj)
                acc[fi][fj] = __builtin_amdgcn_mfma_f32_16x16x32_bf16(
                    bf8[fj].v, af[fi].v, acc[fi][fj], 0, 0, 0);
        __syncthreads();
    }

    // ---- epilogue: add interp (Si), store h1 K-tiled, stats via shfl (no atomics)
    #pragma unroll
    for (int fj = 0; fj < 8; ++fj) {
        int c0 = wc + fj * 16 + q * 4;
        float s[4], sq[4];
        #pragma unroll
        for (int i = 0; i < 4; ++i) { s[i] = 0.0f; sq[i] = 0.0f; }
        #pragma unroll
        for (int fi = 0; fi < 2; ++fi) {
            int rl = wr + fi * 16 + l15;
            int rg = R0 + rl;
            union { float2 f; u16 u[4]; } si;
            si.f = *(const float2*)&Si[rl * 258 + c0];
            union { u16 u[4]; float2 f; } pk;
            #pragma unroll
            for (int i = 0; i < 4; ++i) {
                float v = acc[fi][fj][i] + bf2f(si.u[i]);
                pk.u[i] = f2bf(v);
                s[i] += v; sq[i] += v * v;
            }
            *(float2*)&h1[((size_t)(c0 >> 5) * 65536 + rg) * 32 + (c0 & 31)] = pk.f;
        }
        #pragma unroll
        for (int i = 0; i < 4; ++i) {
            #pragma unroll
            for (int d = 1; d < 16; d <<= 1) {
                s[i]  += __shfl_xor(s[i], d, 16);
                sq[i] += __shfl_xor(sq[i], d, 16);
            }
        }
        if (l15 == 0) {
            int half = w >> 1;
            #pragma unroll
            for (int i = 0; i < 4; ++i) {
                bsum[half][c0 + i] = s[i];
                bsq[half][c0 + i]  = sq[i];
            }
        }
    }
    __syncthreads();
    part1[(size_t)bx * 512 + t * 2 + 0] = bsum[0][t] + bsum[1][t];
    part1[(size_t)bx * 512 + t * 2 + 1] = bsq[0][t] + bsq[1][t];
}

// ---------------------------------------------------------------- stats reduce
__global__ __launch_bounds__(256) void reduce_kernel(
    const float* __restrict__ part, int nblk, int C, float invM,
    const float* __restrict__ gam, const float* __restrict__ bet,
    float* __restrict__ st) {
    __shared__ float red[256];
    int t = threadIdx.x;
    int slot = t & 31, ig = t >> 5;
    int cb = blockIdx.x * 16;
    float p = 0.0f;
    for (int i = ig; i < nblk; i += 8)
        p += part[(size_t)i * (2 * C) + cb * 2 + slot];
    red[t] = p;
    __syncthreads();
    if (t < 32) {
        float tot = red[t];
        #pragma unroll
        for (int k = 1; k < 8; ++k) tot += red[k * 32 + t];
        red[t] = tot;
    }
    __syncthreads();
    if (t < 16) {
        int c = cb + t;
        float sum = red[2 * t], sq = red[2 * t + 1];
        float mean = sum * invM;
        float var  = sq * invM - mean * mean;
        float rs   = rsqrtf(var + 1e-5f);
        float scv  = gam[c] * rs;
        st[c]     = scv;
        st[C + c] = bet[c] - mean * scv;
    }
}

// ---------------------------------------------------------------- GEMM2 v7
// 64x128 tile, grid 1024, LDS dbuf + reg prefetch. Stats: shfl + per-wave
// LDS slices (no atomics).
__global__ __launch_bounds__(256, 4) void gemm2_kernel(
    const u16* __restrict__ h1, const u16* __restrict__ wt2b,
    const float* __restrict__ st1,
    u16* __restrict__ h2, float* __restrict__ part2) {
    __shared__ __align__(16) u16 As[2][64 * 32];
    __shared__ __align__(16) u16 Bs[2][128 * 32];
    __shared__ float sc1[256], sh1[256];
    __shared__ float bsum2[4][128], bsq2[4][128];

    int t = threadIdx.x;
    int bx = blockIdx.x;
    int R0 = bx * 64;
    sc1[t] = st1[t];
    sh1[t] = st1[256 + t];

    int w = t >> 6, l = t & 63, l15 = l & 15, q = l >> 4;
    int wr = w * 16;
    int arow = t >> 2, ac8 = (t & 3) << 3, sa = (arow >> 1) & 3;
    int bm = t >> 1, bh = t & 1, sb = (bm >> 1) & 3;

    union lda_t { float4 f; u16 u[8]; };
    lda_t pa; float4 pb0, pb1;
    const u16* bsrc = wt2b + (size_t)bm * 256 + bh * 16;

    pa.f = *(const float4*)(h1 + ((size_t)0 * 65536 + R0 + arow) * 32 + ac8);
    pb0 = ((const float4*)bsrc)[0];
    pb1 = ((const float4*)bsrc)[1];

    f32x4 acc[8];
    #pragma unroll
    for (int j = 0; j < 8; ++j) acc[j] = (f32x4){0.f, 0.f, 0.f, 0.f};

    __syncthreads();   // sc1/sh1 visible

    {
        float o[8];
        #pragma unroll
        for (int j = 0; j < 8; ++j)
            o[j] = fmaxf(fmaf(bf2f(pa.u[j]), sc1[ac8 + j], sh1[ac8 + j]), 0.0f);
        *(float4*)&As[0][arow * 32 + (((ac8 >> 3) ^ sa) << 3)] = pack8(o);
        *(float4*)&Bs[0][bm * 32 + (((bh * 2 + 0) ^ sb) << 3)] = pb0;
        *(float4*)&Bs[0][bm * 32 + (((bh * 2 + 1) ^ sb) << 3)] = pb1;
    }
    __syncthreads();

    #pragma unroll
    for (int kb = 0; kb < 8; ++kb) {
        if (kb < 7) {
            pa.f = *(const float4*)(h1 + ((size_t)(kb + 1) * 65536 + R0 + arow) * 32 + ac8);
            pb0 = ((const float4*)(bsrc + (kb + 1) * 32))[0];
            pb1 = ((const float4*)(bsrc + (kb + 1) * 32))[1];
        }
        int buf = kb & 1;
        union uf { float4 f; bf16x8 v; };
        uf af, bf8[8];
        {
            int ml = wr + l15;
            af.f = *(const float4*)&As[buf][ml * 32 + ((q ^ ((ml >> 1) & 3)) << 3)];
        }
        #pragma unroll
        for (int fj = 0; fj < 8; ++fj) {
            int nl = fj * 16 + l15;
            bf8[fj].f = *(const float4*)&Bs[buf][nl * 32 + ((q ^ ((nl >> 1) & 3)) << 3)];
        }
        #pragma unroll
        for (int fj = 0; fj < 8; ++fj)
            acc[fj] = __builtin_amdgcn_mfma_f32_16x16x32_bf16(
                bf8[fj].v, af.v, acc[fj], 0, 0, 0);
        if (kb < 7) {
            int ch0 = (kb + 1) * 32 + ac8;
            float o[8];
            #pragma unroll
            for (int j = 0; j < 8; ++j)
                o[j] = fmaxf(fmaf(bf2f(pa.u[j]), sc1[ch0 + j], sh1[ch0 + j]), 0.0f);
            *(float4*)&As[buf ^ 1][arow * 32 + (((ac8 >> 3) ^ sa) << 3)] = pack8(o);
            *(float4*)&Bs[buf ^ 1][bm * 32 + (((bh * 2 + 0) ^ sb) << 3)] = pb0;
            *(float4*)&Bs[buf ^ 1][bm * 32 + (((bh * 2 + 1) ^ sb) << 3)] = pb1;
        }
        __syncthreads();
    }

    // ---- epilogue: h2 store + stats via shfl into per-wave slices (no atomics)
    int rg = R0 + wr + l15;
    #pragma unroll
    for (int fj = 0; fj < 8; ++fj) {
        int cl = fj * 16 + q * 4;
        union { u16 u[4]; float2 f; } pk;
        float s[4], sq[4];
        #pragma unroll
        for (int i = 0; i < 4; ++i) {
            float v = acc[fj][i];
            pk.u[i] = f2bf(v);
            s[i] = v; sq[i] = v * v;
        }
        *(float2*)&h2[(size_t)rg * 128 + cl] = pk.f;
        #pragma unroll
        for (int i = 0; i < 4; ++i) {
            #pragma unroll
            for (int d = 1; d < 16; d <<= 1) {
                s[i]  += __shfl_xor(s[i], d, 16);
                sq[i] += __shfl_xor(sq[i], d, 16);
            }
        }
        if (l15 == 0) {
            #pragma unroll
            for (int i = 0; i < 4; ++i) {
                bsum2[w][cl + i] = s[i];
                bsq2[w][cl + i]  = sq[i];
            }
        }
    }
    __syncthreads();
    if (t < 128) {
        part2[(size_t)bx * 256 + t * 2 + 0] =
            bsum2[0][t] + bsum2[1][t] + bsum2[2][t] + bsum2[3][t];
        part2[(size_t)bx * 256 + t * 2 + 1] =
            bsq2[0][t] + bsq2[1][t] + bsq2[2][t] + bsq2[3][t];
    }
}

// ---------------------------------------------------------------- final BN2 + relu
__global__ __launch_bounds__(256) void final_kernel(
    const u16* __restrict__ h2, const float* __restrict__ st2,
    float* __restrict__ out) {
    __shared__ float lst[256];
    int t = threadIdx.x;
    lst[t] = st2[t];
    __syncthreads();
    size_t e0 = ((size_t)blockIdx.x * 256 + t) * 8;
    int c0 = (int)(e0 & 127);
    union { float4 f; u16 u[8]; } ld;
    ld.f = *(const float4*)(h2 + e0);
    float o[8];
    #pragma unroll
    for (int j = 0; j < 8; ++j) {
        int c = c0 + j;
        float v = fmaf(bf2f(ld.u[j]), lst[c], lst[128 + c]);
        o[j] = fmaxf(v, 0.0f);
    }
    float4* op = (float4*)(out + e0);
    float4 r0; r0.x = o[0]; r0.y = o[1]; r0.z = o[2]; r0.w = o[3];
    float4 r1; r1.x = o[4]; r1.y = o[5]; r1.z = o[6]; r1.w = o[7];
    op[0] = r0;
    op[1] = r1;
}

// ----------------------------------------------------------------
extern "C" void kernel_launch(void* const* d_in, const int* in_sizes, int n_in,
                              void* d_out, int out_size, void* d_ws, size_t ws_size,
                              hipStream_t stream) {
    (void)in_sizes; (void)n_in; (void)out_size; (void)ws_size;
    const float* xyz1    = (const float*)d_in[0];
    const float* xyz2    = (const float*)d_in[1];
    const float* points1 = (const float*)d_in[2];
    const float* points2 = (const float*)d_in[3];
    const float* W1      = (const float*)d_in[4];
    const float* g1      = (const float*)d_in[5];
    const float* b1      = (const float*)d_in[6];
    const float* W2      = (const float*)d_in[7];
    const float* g2      = (const float*)d_in[8];
    const float* b2      = (const float*)d_in[9];

    char* ws = (char*)d_ws;
    int*   idxb = (int*)(ws + OFF_IDX);
    float* wb   = (float*)(ws + OFF_W);
    u16*   wt1b = (u16*)(ws + OFF_WT1B);
    u16*   wt2b = (u16*)(ws + OFF_WT2B);
    float* st1  = (float*)(ws + OFF_ST1);
    float* st2  = (float*)(ws + OFF_ST2);
    float* p1   = (float*)(ws + OFF_P1);
    float* p2   = (float*)(ws + OFF_P2);
    u16*   h1   = (u16*)(ws + OFF_H1);
    u16*   h2   = (u16*)(ws + OFF_H2);
    u16*   G    = (u16*)(ws + OFF_H2);   // reuse: consumed before h2 is written
    float* outp = (float*)d_out;

    prep_kernel<<<320, 256, 0, stream>>>(W1, W2, wt1b, wt2b);
    gemm0_kernel<<<256, 256, 0, stream>>>(points2, wt1b, G);
    knn_kernel<<<2048, 256, 0, stream>>>(xyz1, xyz2, idxb, wb);
    gemm1_kernel<<<1024, 256, 0, stream>>>(points1, G, idxb, wb, wt1b, h1, p1);
    reduce_kernel<<<16, 256, 0, stream>>>(p1, 1024, 256, 1.0f / 65536.0f, g1, b1, st1);
    gemm2_kernel<<<1024, 256, 0, stream>>>(h1, wt2b, st1, h2, p2);
    reduce_kernel<<<8, 256, 0, stream>>>(p2, 1024, 128, 1.0f / 65536.0f, g2, b2, st2);
    final_kernel<<<4096, 256, 0, stream>>>(h2, st2, outp);
}

// Round 4
// 284.812 us; speedup vs baseline: 1.3214x; 1.1003x over previous
//
#include <hip/hip_runtime.h>
#include <hip/hip_bf16.h>

typedef unsigned short u16;
typedef short bf16x8 __attribute__((ext_vector_type(8)));   // 8 bf16 = 4 VGPRs
typedef float f32x4 __attribute__((ext_vector_type(4)));

#define SS_PTS 2048

// workspace byte offsets (all 16B-aligned)
#define OFF_IDX   0ULL         // int  [65536*3]
#define OFF_W     786432ULL    // f32  [65536*3]
#define OFF_WT1B  1572864ULL   // bf16 [256][320]
#define OFF_WT2B  1736704ULL   // bf16 [128][256]
#define OFF_ST1   1802240ULL   // f32  [512]
#define OFF_ST2   1804288ULL   // f32  [256]
#define OFF_P1    1805312ULL   // f32  [1024][512]
#define OFF_P2    3902464ULL   // f32  [1024][256]
#define OFF_H1    4950016ULL   // bf16 tiled [8][65536][32]
#define OFF_H2    38504448ULL  // bf16 [65536][128]; ALSO G [16384][256] bf16
                               // (G consumed by gemm1 before gemm2 writes h2)

__device__ __forceinline__ u16 f2bf(float x) {
    union { __hip_bfloat16 h; u16 u; } cv;
    cv.h = __float2bfloat16(x);
    return cv.u;
}
__device__ __forceinline__ float bf2f(u16 u) {
    union { unsigned int i; float f; } cv;
    cv.i = ((unsigned int)u) << 16;
    return cv.f;
}
__device__ __forceinline__ float4 pack8(const float* v) {
    union { u16 u[8]; float4 f; } pk;
    #pragma unroll
    for (int j = 0; j < 8; ++j) pk.u[j] = f2bf(v[j]);
    return pk.f;
}

// ---------------------------------------------------------------- prep: W -> bf16
__global__ __launch_bounds__(256) void prep_kernel(
    const float* __restrict__ W1, const float* __restrict__ W2,
    u16* __restrict__ wt1b, u16* __restrict__ wt2b) {
    int i = blockIdx.x * 256 + threadIdx.x;
    if (i < 81920) wt1b[i] = f2bf(W1[i]);
    if (i < 32768) wt2b[i] = f2bf(W2[i]);
}

// ---------------------------------------------------------------- GEMM0
// G[16384][256] = points2[16384][256] @ W1b^T  (W1b = wt1b cols 64..319)
__global__ __launch_bounds__(256) void gemm0_kernel(
    const float* __restrict__ points2, const u16* __restrict__ wt1b,
    u16* __restrict__ G) {
    __shared__ __align__(16) u16 Bs[8192];   // 256 rows x 32 k, XOR-swizzled

    int t = threadIdx.x, bx = blockIdx.x;
    int R0 = bx * 64;
    int w = t >> 6, l = t & 63, l15 = l & 15, q = l >> 4;
    int wr = (w >> 1) * 32, wc = (w & 1) * 128;
    int bm = t >> 1, bh = t & 1;
    int sb0 = (bm >> 1) & 3, sb1 = ((bm + 128) >> 1) & 3;
    const u16* wsrc0 = wt1b + (size_t)bm * 320 + 64 + bh * 16;
    const u16* wsrc1 = wt1b + (size_t)(bm + 128) * 320 + 64 + bh * 16;

    float4 pb0 = ((const float4*)wsrc0)[0], pb1 = ((const float4*)wsrc0)[1];
    float4 pb2 = ((const float4*)wsrc1)[0], pb3 = ((const float4*)wsrc1)[1];

    f32x4 acc[2][8];
    #pragma unroll
    for (int i = 0; i < 2; ++i)
        #pragma unroll
        for (int j = 0; j < 8; ++j) acc[i][j] = (f32x4){0.f, 0.f, 0.f, 0.f};

    #pragma unroll
    for (int kb = 0; kb < 8; ++kb) {
        *(float4*)&Bs[bm * 32 + (((bh * 2 + 0) ^ sb0) << 3)] = pb0;
        *(float4*)&Bs[bm * 32 + (((bh * 2 + 1) ^ sb0) << 3)] = pb1;
        *(float4*)&Bs[(bm + 128) * 32 + (((bh * 2 + 0) ^ sb1) << 3)] = pb2;
        *(float4*)&Bs[(bm + 128) * 32 + (((bh * 2 + 1) ^ sb1) << 3)] = pb3;
        __syncthreads();
        if (kb < 7) {
            pb0 = ((const float4*)(wsrc0 + (kb + 1) * 32))[0];
            pb1 = ((const float4*)(wsrc0 + (kb + 1) * 32))[1];
            pb2 = ((const float4*)(wsrc1 + (kb + 1) * 32))[0];
            pb3 = ((const float4*)(wsrc1 + (kb + 1) * 32))[1];
        }
        union uf { float4 f; bf16x8 v; };
        uf af[2], bf8[8];
        #pragma unroll
        for (int fi = 0; fi < 2; ++fi) {
            int ml = wr + fi * 16 + l15;
            const float* s = points2 + (size_t)(R0 + ml) * 256 + kb * 32 + q * 8;
            float4 x0 = ((const float4*)s)[0], x1 = ((const float4*)s)[1];
            float va[8] = {x0.x, x0.y, x0.z, x0.w, x1.x, x1.y, x1.z, x1.w};
            af[fi].f = pack8(va);
        }
        #pragma unroll
        for (int fj = 0; fj < 8; ++fj) {
            int nl = wc + fj * 16 + l15;
            bf8[fj].f = *(const float4*)&Bs[nl * 32 + ((q ^ ((nl >> 1) & 3)) << 3)];
        }
        #pragma unroll
        for (int fi = 0; fi < 2; ++fi)
            #pragma unroll
            for (int fj = 0; fj < 8; ++fj)
                acc[fi][fj] = __builtin_amdgcn_mfma_f32_16x16x32_bf16(
                    bf8[fj].v, af[fi].v, acc[fi][fj], 0, 0, 0);
        __syncthreads();
    }

    #pragma unroll
    for (int fi = 0; fi < 2; ++fi) {
        int rg = R0 + wr + fi * 16 + l15;
        #pragma unroll
        for (int fj = 0; fj < 8; ++fj) {
            int cl = wc + fj * 16 + q * 4;
            union { u16 u[4]; float2 f; } pk;
            #pragma unroll
            for (int i = 0; i < 4; ++i) pk.u[i] = f2bf(acc[fi][fj][i]);
            *(float2*)&G[(size_t)rg * 256 + cl] = pk.f;
        }
    }
}

// ---------------------------------------------------------------- 3-NN + weights
// v9: packed-key top-3. sc = |p-q|^2 + 4 in [4,36) -> (bits(sc)-bits(4.0))
// is a 25-bit monotone injective int; pack 7-bit in-partition index in the
// low bits -> sorted-3 insert is min_u32 + 2x med3_u32, ZERO cmp/cndmask.
// Exact f32 ordering for all d^2 < 32 (top-3 is << 8 for every query);
// >=32 saturates (never a true top-3). Low-clamp guards d^2~0 rounding.
// 2048 blocks x 32 queries (R=2/thread, P=16 partitions of 128) -> 4 blk/CU.
// Winner distances recomputed exactly from LDS for the weights.
__global__ __launch_bounds__(256) void knn_kernel(
    const float* __restrict__ xyz1, const float* __restrict__ xyz2,
    int* __restrict__ idxb, float* __restrict__ wb) {
    __shared__ float4 pts[2064];              // 16 regions of 129 (bank stagger)
    __shared__ unsigned int ck[16][16][2][3]; // [g][p][r][e] packed keys
    int t = threadIdx.x;
    int bx = blockIdx.x;
    int b = bx >> 8;                          // batch (256 blocks per batch)
    int q0 = (bx & 255) << 5;                 // 32 queries per block
    const float* x2b = xyz2 + (size_t)b * SS_PTS * 3;
    for (int j = t; j < SS_PTS; j += 256) {
        float x = x2b[j * 3 + 0], y = x2b[j * 3 + 1], z = x2b[j * 3 + 2];
        float pw4 = fmaf(x, x, fmaf(y, y, fmaf(z, z, 4.0f)));
        pts[(j >> 7) * 129 + (j & 127)] = make_float4(x, y, z, pw4);
    }
    int g = t >> 4, p = t & 15;
    size_t qb = (size_t)b * 8192 + q0 + g * 2;
    float m2x[2], m2y[2], m2z[2], qq[2];
    #pragma unroll
    for (int r = 0; r < 2; ++r) {
        float qx = xyz1[(qb + r) * 3 + 0];
        float qy = xyz1[(qb + r) * 3 + 1];
        float qz = xyz1[(qb + r) * 3 + 2];
        m2x[r] = -2.0f * qx; m2y[r] = -2.0f * qy; m2z[r] = -2.0f * qz;
        qq[r] = fmaf(qx, qx, fmaf(qy, qy, qz * qz));
    }
    unsigned int k0[2], k1[2], k2[2];
    #pragma unroll
    for (int r = 0; r < 2; ++r) { k0[r] = 0xFFFFFFFFu; k1[r] = 0xFFFFFFFFu; k2[r] = 0xFFFFFFFFu; }
    __syncthreads();

    const int BASE_BITS = 0x40800000;         // bits(4.0f)
    const int KD_CAP    = 0x01900000 - 1;     // bits(36.0f)-bits(4.0f)-1, 25-bit
    int base = p * 129;                       // float4 index of partition start
    #pragma unroll 4
    for (int s = 0; s < 128; ++s) {
        float4 pt = pts[base + s];
        #pragma unroll
        for (int r = 0; r < 2; ++r) {
            float sc = fmaf(m2x[r], pt.x, fmaf(m2y[r], pt.y, fmaf(m2z[r], pt.z, pt.w))) + qq[r];
            int su = (int)__float_as_uint(sc) - BASE_BITS;
            int kd = su < 0 ? 0 : (su > KD_CAP ? KD_CAP : su);   // med3_i32
            unsigned int key = ((unsigned int)kd << 7) | (unsigned int)s;
            unsigned int o0 = k0[r], o1 = k1[r];
            unsigned int mx0 = key > o0 ? key : o0;
            unsigned int mx1 = key > o1 ? key : o1;
            k0[r] = key < o0 ? key : o0;                          // min_u32
            k1[r] = mx0 < k1[r] ? mx0 : k1[r];                    // med3_u32
            k2[r] = mx1 < k2[r] ? mx1 : k2[r];                    // med3_u32
        }
    }

    #pragma unroll
    for (int r = 0; r < 2; ++r) {
        ck[g][p][r][0] = k0[r]; ck[g][p][r][1] = k1[r]; ck[g][p][r][2] = k2[r];
    }
    __syncthreads();

    // merge: thread t (t<32) owns query q0+t; 16 partitions x 3 candidates.
    if (t < 32) {
        int mg = t >> 1, mr = t & 1;
        unsigned int e0 = 0xFFFFFFFFu, e1 = 0xFFFFFFFFu, e2 = 0xFFFFFFFFu;
        int J0 = 0, J1 = 0, J2 = 0;
        #pragma unroll
        for (int pp = 0; pp < 16; ++pp) {
            #pragma unroll
            for (int e = 0; e < 3; ++e) {
                unsigned int key = ck[mg][pp][mr][e];
                int sj = pp * 128 + (int)(key & 127u);
                bool c0 = key < e0, c1 = key < e1, c2 = key < e2;
                unsigned int o0 = e0, o1 = e1;
                unsigned int mx0 = key > o0 ? key : o0;
                unsigned int mx1 = key > o1 ? key : o1;
                e0 = key < o0 ? key : o0;
                e1 = mx0 < e1 ? mx0 : e1;
                e2 = mx1 < e2 ? mx1 : e2;
                int nJ0 = c0 ? sj : J0;
                int nJ1 = c1 ? (c0 ? J0 : sj) : J1;
                int nJ2 = c2 ? (c1 ? J1 : sj) : J2;
                J0 = nJ0; J1 = nJ1; J2 = nJ2;
            }
        }
        size_t gq = (size_t)b * 8192 + q0 + t;
        float qx = xyz1[gq * 3 + 0], qy = xyz1[gq * 3 + 1], qz = xyz1[gq * 3 + 2];
        // exact distance recompute for the 3 winners
        float4 p0 = pts[(J0 >> 7) * 129 + (J0 & 127)];
        float4 p1 = pts[(J1 >> 7) * 129 + (J1 & 127)];
        float4 p2 = pts[(J2 >> 7) * 129 + (J2 & 127)];
        float dx0 = p0.x - qx, dy0 = p0.y - qy, dz0 = p0.z - qz;
        float dx1 = p1.x - qx, dy1 = p1.y - qy, dz1 = p1.z - qz;
        float dx2 = p2.x - qx, dy2 = p2.y - qy, dz2 = p2.z - qz;
        float dd0 = fmaxf(fmaf(dx0, dx0, fmaf(dy0, dy0, dz0 * dz0)), 1e-10f);
        float dd1 = fmaxf(fmaf(dx1, dx1, fmaf(dy1, dy1, dz1 * dz1)), 1e-10f);
        float dd2 = fmaxf(fmaf(dx2, dx2, fmaf(dy2, dy2, dz2 * dz2)), 1e-10f);
        float w0 = 1.0f / dd0, w1 = 1.0f / dd1, w2 = 1.0f / dd2;
        float inv = 1.0f / (w0 + w1 + w2);
        idxb[gq * 3 + 0] = J0;
        idxb[gq * 3 + 1] = J1;
        idxb[gq * 3 + 2] = J2;
        wb[gq * 3 + 0] = w0 * inv;
        wb[gq * 3 + 1] = w1 * inv;
        wb[gq * 3 + 2] = w2 * inv;
    }
}

// ---------------------------------------------------------------- GEMM1 v7
// h1 = points1 @ W1a^T (K=64 MFMA) + Sum_k w_k * G[idx_k].
// v7: NO LDS atomics — stats via shfl-reduce over the 16 row-lanes into
// per-wave-pair LDS slices (each slot written by exactly one lane).
// idx/w read via uniform-address broadcast loads (no LDS staging).
__global__ __launch_bounds__(256, 3) void gemm1_kernel(
    const float* __restrict__ points1, const u16* __restrict__ G,
    const int* __restrict__ idxb, const float* __restrict__ wb,
    const u16* __restrict__ wt1b, u16* __restrict__ h1, float* __restrict__ part1) {
    __shared__ __align__(16) u16 Si[64 * 258];     // interp bf16, stride 258
    __shared__ __align__(16) u16 Bs[8192];         // W1a tile 256x32, swizzled
    __shared__ float bsum[2][256], bsq[2][256];    // per-wave-pair slices

    int t = threadIdx.x, bx = blockIdx.x;
    int batch = bx & 7;
    int R0 = batch * 8192 + (bx >> 3) * 64;
    const u16* Gb = G + (size_t)batch * SS_PTS * 256;

    int w = t >> 6, l = t & 63, l15 = l & 15, q = l >> 4;
    int wr = (w >> 1) * 32, wc = (w & 1) * 128;

    // ---- phase 1: gather-sum from G into Si; one wave per query row
    {
        #pragma unroll 4
        for (int e = 0; e < 16; ++e) {
            int qi = w * 16 + e;
            size_t gq = (size_t)(R0 + qi) * 3;
            int i0 = idxb[gq + 0], i1 = idxb[gq + 1], i2 = idxb[gq + 2];
            float w0 = wb[gq + 0], w1 = wb[gq + 1], w2 = wb[gq + 2];
            union { float2 f; u16 u[4]; } g0, g1, g2;
            g0.f = *(const float2*)(Gb + (size_t)i0 * 256 + l * 4);
            g1.f = *(const float2*)(Gb + (size_t)i1 * 256 + l * 4);
            g2.f = *(const float2*)(Gb + (size_t)i2 * 256 + l * 4);
            union { u16 u[4]; float2 f; } pk;
            #pragma unroll
            for (int i = 0; i < 4; ++i) {
                float v = fmaf(w0, bf2f(g0.u[i]),
                          fmaf(w1, bf2f(g1.u[i]), w2 * bf2f(g2.u[i])));
                pk.u[i] = f2bf(v);
            }
            *(float2*)&Si[qi * 258 + l * 4] = pk.f;
        }
    }

    // ---- B staging regs (W1a rows, k 0..63)
    int bm = t >> 1, bh = t & 1;
    int sb0 = (bm >> 1) & 3, sb1 = ((bm + 128) >> 1) & 3;
    const u16* wsrc0 = wt1b + (size_t)bm * 320 + bh * 16;
    const u16* wsrc1 = wt1b + (size_t)(bm + 128) * 320 + bh * 16;
    float4 pb0 = ((const float4*)wsrc0)[0], pb1 = ((const float4*)wsrc0)[1];
    float4 pb2 = ((const float4*)wsrc1)[0], pb3 = ((const float4*)wsrc1)[1];

    f32x4 acc[2][8];
    #pragma unroll
    for (int i = 0; i < 2; ++i)
        #pragma unroll
        for (int j = 0; j < 8; ++j) acc[i][j] = (f32x4){0.f, 0.f, 0.f, 0.f};

    // ---- phase 2: K-loop (2 x K=32) on points1 @ W1a^T
    #pragma unroll
    for (int kb = 0; kb < 2; ++kb) {
        *(float4*)&Bs[bm * 32 + (((bh * 2 + 0) ^ sb0) << 3)] = pb0;
        *(float4*)&Bs[bm * 32 + (((bh * 2 + 1) ^ sb0) << 3)] = pb1;
        *(float4*)&Bs[(bm + 128) * 32 + (((bh * 2 + 0) ^ sb1) << 3)] = pb2;
        *(float4*)&Bs[(bm + 128) * 32 + (((bh * 2 + 1) ^ sb1) << 3)] = pb3;
        __syncthreads();
        if (kb == 0) {
            pb0 = ((const float4*)(wsrc0 + 32))[0];
            pb1 = ((const float4*)(wsrc0 + 32))[1];
            pb2 = ((const float4*)(wsrc1 + 32))[0];
            pb3 = ((const float4*)(wsrc1 + 32))[1];
        }
        union uf { float4 f; bf16x8 v; };
        uf af[2], bf8[8];
        #pragma unroll
        for (int fi = 0; fi < 2; ++fi) {
            int ml = wr + fi * 16 + l15;
            const float* s = points1 + (size_t)(R0 + ml) * 64 + kb * 32 + q * 8;
            float4 x0 = ((const float4*)s)[0], x1 = ((const float4*)s)[1];
            float va[8] = {x0.x, x0.y, x0.z, x0.w, x1.x, x1.y, x1.z, x1.w};
            af[fi].f = pack8(va);
        }
        #pragma unroll
        for (int fj = 0; fj < 8; ++fj) {
            int nl = wc + fj * 16 + l15;
            bf8[fj].f = *(const float4*)&Bs[nl * 32 + ((q ^ ((nl >> 1) & 3)) << 3)];
        }
        #pragma unroll
        for (int fi = 0; fi < 2; ++fi)
            #pragma unroll
            for (int fj = 0; fj < 8; ++fj)
                acc[fi][fj] = __builtin_amdgcn_mfma_f32_16x16x32_bf16(
                    bf8[fj].v, af[fi].v, acc[fi][fj], 0, 0, 0);
        __syncthreads();
    }

    // ---- epilogue: add interp (Si), store h1 K-tiled, stats via shfl (no atomics)
    #pragma unroll
    for (int fj = 0; fj < 8; ++fj) {
        int c0 = wc + fj * 16 + q * 4;
        float s[4], sq[4];
        #pragma unroll
        for (int i = 0; i < 4; ++i) { s[i] = 0.0f; sq[i] = 0.0f; }
        #pragma unroll
        for (int fi = 0; fi < 2; ++fi) {
            int rl = wr + fi * 16 + l15;
            int rg = R0 + rl;
            union { float2 f; u16 u[4]; } si;
            si.f = *(const float2*)&Si[rl * 258 + c0];
            union { u16 u[4]; float2 f; } pk;
            #pragma unroll
            for (int i = 0; i < 4; ++i) {
                float v = acc[fi][fj][i] + bf2f(si.u[i]);
                pk.u[i] = f2bf(v);
                s[i] += v; sq[i] += v * v;
            }
            *(float2*)&h1[((size_t)(c0 >> 5) * 65536 + rg) * 32 + (c0 & 31)] = pk.f;
        }
        #pragma unroll
        for (int i = 0; i < 4; ++i) {
            #pragma unroll
            for (int d = 1; d < 16; d <<= 1) {
                s[i]  += __shfl_xor(s[i], d, 16);
                sq[i] += __shfl_xor(sq[i], d, 16);
            }
        }
        if (l15 == 0) {
            int half = w >> 1;
            #pragma unroll
            for (int i = 0; i < 4; ++i) {
                bsum[half][c0 + i] = s[i];
                bsq[half][c0 + i]  = sq[i];
            }
        }
    }
    __syncthreads();
    part1[(size_t)bx * 512 + t * 2 + 0] = bsum[0][t] + bsum[1][t];
    part1[(size_t)bx * 512 + t * 2 + 1] = bsq[0][t] + bsq[1][t];
}

// ---------------------------------------------------------------- stats reduce
__global__ __launch_bounds__(256) void reduce_kernel(
    const float* __restrict__ part, int nblk, int C, float invM,
    const float* __restrict__ gam, const float* __restrict__ bet,
    float* __restrict__ st) {
    __shared__ float red[256];
    int t = threadIdx.x;
    int slot = t & 31, ig = t >> 5;
    int cb = blockIdx.x * 16;
    float p = 0.0f;
    for (int i = ig; i < nblk; i += 8)
        p += part[(size_t)i * (2 * C) + cb * 2 + slot];
    red[t] = p;
    __syncthreads();
    if (t < 32) {
        float tot = red[t];
        #pragma unroll
        for (int k = 1; k < 8; ++k) tot += red[k * 32 + t];
        red[t] = tot;
    }
    __syncthreads();
    if (t < 16) {
        int c = cb + t;
        float sum = red[2 * t], sq = red[2 * t + 1];
        float mean = sum * invM;
        float var  = sq * invM - mean * mean;
        float rs   = rsqrtf(var + 1e-5f);
        float scv  = gam[c] * rs;
        st[c]     = scv;
        st[C + c] = bet[c] - mean * scv;
    }
}

// ---------------------------------------------------------------- GEMM2 v8
// Barrier-free direct-from-global MFMA. Both operand fragments are loadable
// with the exact per-lane MFMA layout: h1 is K-tiled [8][65536][32] (a frag
// = 16 contiguous rows x 64B = one coalesced 1KB wave read); wt2b rows give
// the B frag (64KB, L2-resident). BN1+ReLU fused into the A-frag load
// (identical pack8(relu(fma)) math as the old LDS-stage -> bit-identical).
// No LDS staging, no per-K-step barriers, no vmcnt(0) drains: the unrolled
// K-loop lets the compiler pipeline 10 independent loads/step arbitrarily
// deep. 128 rows/block (32/wave), grid 512.
__global__ __launch_bounds__(256, 2) void gemm2_kernel(
    const u16* __restrict__ h1, const u16* __restrict__ wt2b,
    const float* __restrict__ st1,
    u16* __restrict__ h2, float* __restrict__ part2) {
    __shared__ float sc1[256], sh1[256];
    __shared__ float bsum2[4][128], bsq2[4][128];

    int t = threadIdx.x;
    int bx = blockIdx.x;
    int R0 = bx * 128;
    sc1[t] = st1[t];
    sh1[t] = st1[256 + t];

    int w = t >> 6, l = t & 63, l15 = l & 15, q = l >> 4;
    int rowb = R0 + w * 32;          // wave's 32 rows

    f32x4 acc[2][8];
    #pragma unroll
    for (int i = 0; i < 2; ++i)
        #pragma unroll
        for (int j = 0; j < 8; ++j) acc[i][j] = (f32x4){0.f, 0.f, 0.f, 0.f};

    __syncthreads();   // sc1/sh1 visible

    union uf { float4 f; bf16x8 v; };
    union lu { float4 f; u16 u[8]; };

    #pragma unroll
    for (int kb = 0; kb < 8; ++kb) {
        int c0 = kb * 32 + q * 8;
        lu ra0, ra1;
        ra0.f = *(const float4*)(h1 + ((size_t)kb * 65536 + rowb + l15) * 32 + q * 8);
        ra1.f = *(const float4*)(h1 + ((size_t)kb * 65536 + rowb + 16 + l15) * 32 + q * 8);
        uf bf8[8];
        #pragma unroll
        for (int fj = 0; fj < 8; ++fj)
            bf8[fj].f = *(const float4*)(wt2b + (size_t)(fj * 16 + l15) * 256 + c0);
        float scv[8], shv[8];
        *(float4*)&scv[0] = *(const float4*)&sc1[c0];
        *(float4*)&scv[4] = *(const float4*)&sc1[c0 + 4];
        *(float4*)&shv[0] = *(const float4*)&sh1[c0];
        *(float4*)&shv[4] = *(const float4*)&sh1[c0 + 4];
        float o0[8], o1[8];
        #pragma unroll
        for (int j = 0; j < 8; ++j) {
            o0[j] = fmaxf(fmaf(bf2f(ra0.u[j]), scv[j], shv[j]), 0.0f);
            o1[j] = fmaxf(fmaf(bf2f(ra1.u[j]), scv[j], shv[j]), 0.0f);
        }
        uf af0, af1;
        af0.f = pack8(o0);
        af1.f = pack8(o1);
        #pragma unroll
        for (int fj = 0; fj < 8; ++fj)
            acc[0][fj] = __builtin_amdgcn_mfma_f32_16x16x32_bf16(
                bf8[fj].v, af0.v, acc[0][fj], 0, 0, 0);
        #pragma unroll
        for (int fj = 0; fj < 8; ++fj)
            acc[1][fj] = __builtin_amdgcn_mfma_f32_16x16x32_bf16(
                bf8[fj].v, af1.v, acc[1][fj], 0, 0, 0);
    }

    // ---- epilogue: h2 store + stats via shfl into per-wave slices (no atomics)
    #pragma unroll
    for (int fj = 0; fj < 8; ++fj) {
        int cl = fj * 16 + q * 4;
        float s[4], sq[4];
        #pragma unroll
        for (int i = 0; i < 4; ++i) { s[i] = 0.0f; sq[i] = 0.0f; }
        #pragma unroll
        for (int fi = 0; fi < 2; ++fi) {
            int rg = rowb + fi * 16 + l15;
            union { u16 u[4]; float2 f; } pk;
            #pragma unroll
            for (int i = 0; i < 4; ++i) {
                float v = acc[fi][fj][i];
                pk.u[i] = f2bf(v);
                s[i] += v; sq[i] += v * v;
            }
            *(float2*)&h2[(size_t)rg * 128 + cl] = pk.f;
        }
        #pragma unroll
        for (int i = 0; i < 4; ++i) {
            #pragma unroll
            for (int d = 1; d < 16; d <<= 1) {
                s[i]  += __shfl_xor(s[i], d, 16);
                sq[i] += __shfl_xor(sq[i], d, 16);
            }
        }
        if (l15 == 0) {
            #pragma unroll
            for (int i = 0; i < 4; ++i) {
                bsum2[w][cl + i] = s[i];
                bsq2[w][cl + i]  = sq[i];
            }
        }
    }
    __syncthreads();
    if (t < 128) {
        part2[(size_t)bx * 256 + t * 2 + 0] =
            bsum2[0][t] + bsum2[1][t] + bsum2[2][t] + bsum2[3][t];
        part2[(size_t)bx * 256 + t * 2 + 1] =
            bsq2[0][t] + bsq2[1][t] + bsq2[2][t] + bsq2[3][t];
    }
}

// ---------------------------------------------------------------- final BN2 + relu
__global__ __launch_bounds__(256) void final_kernel(
    const u16* __restrict__ h2, const float* __restrict__ st2,
    float* __restrict__ out) {
    __shared__ float lst[256];
    int t = threadIdx.x;
    lst[t] = st2[t];
    __syncthreads();
    size_t e0 = ((size_t)blockIdx.x * 256 + t) * 8;
    int c0 = (int)(e0 & 127);
    union { float4 f; u16 u[8]; } ld;
    ld.f = *(const float4*)(h2 + e0);
    float o[8];
    #pragma unroll
    for (int j = 0; j < 8; ++j) {
        int c = c0 + j;
        float v = fmaf(bf2f(ld.u[j]), lst[c], lst[128 + c]);
        o[j] = fmaxf(v, 0.0f);
    }
    float4* op = (float4*)(out + e0);
    float4 r0; r0.x = o[0]; r0.y = o[1]; r0.z = o[2]; r0.w = o[3];
    float4 r1; r1.x = o[4]; r1.y = o[5]; r1.z = o[6]; r1.w = o[7];
    op[0] = r0;
    op[1] = r1;
}

// ----------------------------------------------------------------
extern "C" void kernel_launch(void* const* d_in, const int* in_sizes, int n_in,
                              void* d_out, int out_size, void* d_ws, size_t ws_size,
                              hipStream_t stream) {
    (void)in_sizes; (void)n_in; (void)out_size; (void)ws_size;
    const float* xyz1    = (const float*)d_in[0];
    const float* xyz2    = (const float*)d_in[1];
    const float* points1 = (const float*)d_in[2];
    const float* points2 = (const float*)d_in[3];
    const float* W1      = (const float*)d_in[4];
    const float* g1      = (const float*)d_in[5];
    const float* b1      = (const float*)d_in[6];
    const float* W2      = (const float*)d_in[7];
    const float* g2      = (const float*)d_in[8];
    const float* b2      = (const float*)d_in[9];

    char* ws = (char*)d_ws;
    int*   idxb = (int*)(ws + OFF_IDX);
    float* wb   = (float*)(ws + OFF_W);
    u16*   wt1b = (u16*)(ws + OFF_WT1B);
    u16*   wt2b = (u16*)(ws + OFF_WT2B);
    float* st1  = (float*)(ws + OFF_ST1);
    float* st2  = (float*)(ws + OFF_ST2);
    float* p1   = (float*)(ws + OFF_P1);
    float* p2   = (float*)(ws + OFF_P2);
    u16*   h1   = (u16*)(ws + OFF_H1);
    u16*   h2   = (u16*)(ws + OFF_H2);
    u16*   G    = (u16*)(ws + OFF_H2);   // reuse: consumed before h2 is written
    float* outp = (float*)d_out;

    prep_kernel<<<320, 256, 0, stream>>>(W1, W2, wt1b, wt2b);
    gemm0_kernel<<<256, 256, 0, stream>>>(points2, wt1b, G);
    knn_kernel<<<2048, 256, 0, stream>>>(xyz1, xyz2, idxb, wb);
    gemm1_kernel<<<1024, 256, 0, stream>>>(points1, G, idxb, wb, wt1b, h1, p1);
    reduce_kernel<<<16, 256, 0, stream>>>(p1, 1024, 256, 1.0f / 65536.0f, g1, b1, st1);
    gemm2_kernel<<<512, 256, 0, stream>>>(h1, wt2b, st1, h2, p2);
    reduce_kernel<<<8, 256, 0, stream>>>(p2, 512, 128, 1.0f / 65536.0f, g2, b2, st2);
    final_kernel<<<4096, 256, 0, stream>>>(h2, st2, outp);
}